// Round 5
// baseline (438.646 us; speedup 1.0000x reference)
//
#include <hip/hip_runtime.h>
#include <hip/hip_bf16.h>

#define SEQ 4096
#define MTOT 16384

typedef float f32x4  __attribute__((ext_vector_type(4)));
typedef float f32x16 __attribute__((ext_vector_type(16)));
typedef _Float16 f16;
typedef _Float16 f16x8 __attribute__((ext_vector_type(8)));
typedef unsigned int   u32;
typedef unsigned int   u32x4 __attribute__((ext_vector_type(4)));
typedef unsigned short u16;

// ws byte offsets
static constexpr size_t QS_B   = 0;          // fp16 Q (pre-scaled) [16384][64]  2MB
static constexpr size_t KS_B   = 2u << 20;   // fp16 K [16384][64]               2MB
static constexpr size_t VT_B   = 4u << 20;   // fp16 V^T [4][64][4096]           2MB
static constexpr size_t W16_B  = 6u << 20;   // fp16 W [192][512] (Wq scaled)  192KB
static constexpr size_t PART_B = 8u << 20;   // fp32 partial O: 2 x [16384][64]  8MB
static constexpr size_t ML_B   = 16u << 20;  // fp32 m[2][16384] then l[2][16384]

__device__ __forceinline__ u16 h16(float v) { return __builtin_bit_cast(u16, (f16)v); }
__device__ __forceinline__ u32 pkrtz(float a, float b) {
  return __builtin_bit_cast(u32, __builtin_amdgcn_cvt_pkrtz(a, b));
}

// ---------------- W fp32 -> fp16 (Wq folded with 0.125*log2e) ----------------
__global__ __launch_bounds__(256) void wconv_kernel(const float* __restrict__ Wq,
                                                    const float* __restrict__ Wk,
                                                    const float* __restrict__ Wv,
                                                    u16* __restrict__ w16) {
  const float QSC = 0.18033688011112042f;  // 0.125 * log2(e)
  int e = (blockIdx.x * 256 + threadIdx.x) * 4;  // [0, 98304)
  int mat = e >> 15;
  const float* W = (mat == 0) ? Wq : (mat == 1 ? Wk : Wv);
  f32x4 v = *(const f32x4*)(W + (e & 32767));
  if (mat == 0) v *= QSC;
  __attribute__((aligned(8))) u16 b[4];
#pragma unroll
  for (int j = 0; j < 4; ++j) b[j] = h16(v[j]);
  *(uint2*)(w16 + e) = *(uint2*)b;
}

// ---------------- QKV projection: direct-from-global fragments, no main-loop LDS ----
// 512 blocks x 256 thr (4 waves). Block: 32 x-rows. Wave (mg,ng): rows mg*16..+15,
// cols ng*96..+95 (6 subtiles). K=512 in 16 steps of 32.
__global__ __launch_bounds__(256, 4) void proj_kernel(const float* __restrict__ x,
                                                      const u16* __restrict__ w16,
                                                      u16* __restrict__ ws) {
  __shared__ float scr[32 * 193];

  const int tid  = threadIdx.x;
  const int blk  = blockIdx.x;
  const int lane = tid & 63;
  const int w    = tid >> 6;
  const int r16  = lane & 15;
  const int g    = lane >> 4;
  const int mg   = w & 1;
  const int ng   = w >> 1;
  const int m0   = blk * 32 + mg * 16;

  f32x4 acc[6];
#pragma unroll
  for (int s = 0; s < 6; ++s) acc[s] = (f32x4){0.f, 0.f, 0.f, 0.f};

#pragma unroll 2
  for (int step = 0; step < 16; ++step) {
    const int k0 = step * 32;
    const float* xp = x + (size_t)(m0 + r16) * 512 + k0 + g * 8;
    f32x4 xa = *(const f32x4*)xp;
    f32x4 xb = *(const f32x4*)(xp + 4);
    f16x8 a;
#pragma unroll
    for (int j = 0; j < 4; ++j) { a[j] = (f16)xa[j]; a[4 + j] = (f16)xb[j]; }
#pragma unroll
    for (int s = 0; s < 6; ++s) {
      f16x8 b = *(const f16x8*)(w16 + (size_t)(ng * 96 + s * 16 + r16) * 512 + k0 + g * 8);
      acc[s] = __builtin_amdgcn_mfma_f32_16x16x32_f16(a, b, acc[s], 0, 0, 0);
    }
  }

  // dump to LDS scratch: row_local = mg*16 + g*4 + rr, col = ng*96 + s*16 + r16
#pragma unroll
  for (int s = 0; s < 6; ++s)
#pragma unroll
    for (int rr = 0; rr < 4; ++rr)
      scr[(mg * 16 + g * 4 + rr) * 193 + ng * 96 + s * 16 + r16] = acc[s][rr];
  __syncthreads();

  u16* Qs = ws + (QS_B >> 1);
  u16* Ks = ws + (KS_B >> 1);
  u16* Vt = ws + (VT_B >> 1);
  // Q and K rows (fp16, row-major)
  {
    int row = tid >> 3, c0 = (tid & 7) * 8;
    __attribute__((aligned(16))) u16 bq[8], bk[8];
#pragma unroll
    for (int j = 0; j < 8; ++j) {
      bq[j] = h16(scr[row * 193 + c0 + j]);
      bk[j] = h16(scr[row * 193 + 64 + c0 + j]);
    }
    *(uint4*)(Qs + (size_t)(blk * 32 + row) * 64 + c0) = *(uint4*)bq;
    *(uint4*)(Ks + (size_t)(blk * 32 + row) * 64 + c0) = *(uint4*)bk;
  }
  // V^T
  {
    int d = tid >> 2, sg = (tid & 3) * 8;
    int bb = blk >> 7, s0 = (blk * 32) & 4095;
    __attribute__((aligned(16))) u16 bv[8];
#pragma unroll
    for (int j = 0; j < 8; ++j) bv[j] = h16(scr[(sg + j) * 193 + 128 + d]);
    *(uint4*)(Vt + (size_t)(bb * 64 + d) * SEQ + s0 + sg) = *(uint4*)bv;
  }
}

// ---------------- flash attention: grid (256 q-tiles, 2 kv-splits) x 512 thr ----------
// 8 waves; wave w covers tiles t = sp*32 + i*8 + w (i=0..3); in-LDS 8-wave merge;
// unnormalized partials + (m,l) to ws; cross-split merge kernel.
__global__ __launch_bounds__(512, 4) void attn_kernel(u16* __restrict__ ws) {
  __shared__ float oaccs[64][68];
  __shared__ float mls[8][64][2];

  const int tid  = threadIdx.x;
  const int w    = tid >> 6;
  const int lane = tid & 63;
  const int l31  = lane & 31;
  const int h    = lane >> 5;
  const int qt   = blockIdx.x;   // 0..255
  const int sp   = blockIdx.y;   // 0..1
  const int bb   = qt >> 6;

  const u16* Qg = ws + (QS_B >> 1);
  const u16* Kg = ws + (KS_B >> 1) + (size_t)bb * SEQ * 64;
  const u16* Vg = ws + (VT_B >> 1) + (size_t)bb * 64 * SEQ;

  f16x8 qf[2][4];
#pragma unroll
  for (int qk = 0; qk < 2; ++qk)
#pragma unroll
    for (int ch = 0; ch < 4; ++ch)
      qf[qk][ch] = *(const f16x8*)(Qg + (size_t)(qt * 64 + qk * 32 + l31) * 64 + ch * 16 + h * 8);

  f32x16 oacc[2][2];  // [dblk][qblk] O^T
#pragma unroll
  for (int a = 0; a < 2; ++a)
#pragma unroll
    for (int b = 0; b < 2; ++b)
#pragma unroll
      for (int r = 0; r < 16; ++r) oacc[a][b][r] = 0.f;
  float mrun[2] = {-INFINITY, -INFINITY};
  float lrun[2] = {0.f, 0.f};
  const float RTHR = 11.0f;  // defer-max threshold (exp2 domain): P <= 2^11

  // prefetch K tile i=0
  f16x8 ka[2][4];
  {
    const int t0 = sp * 32 + w;
#pragma unroll
    for (int kb = 0; kb < 2; ++kb)
#pragma unroll
      for (int ch = 0; ch < 4; ++ch)
        ka[kb][ch] = *(const f16x8*)(Kg + (size_t)(t0 * 64 + kb * 32 + l31) * 64 + ch * 16 + h * 8);
  }

#pragma unroll 1
  for (int i = 0; i < 4; ++i) {
    const int t = sp * 32 + i * 8 + w;
    f16x8 vf[2][4];
#pragma unroll
    for (int db = 0; db < 2; ++db)
#pragma unroll
      for (int ch = 0; ch < 4; ++ch)
        vf[db][ch] = *(const f16x8*)(Vg + (size_t)(db * 32 + l31) * SEQ + t * 64 + ch * 16 + h * 8);

    f32x16 sac[2][2];
#pragma unroll
    for (int a = 0; a < 2; ++a)
#pragma unroll
      for (int b = 0; b < 2; ++b)
#pragma unroll
        for (int r = 0; r < 16; ++r) sac[a][b][r] = 0.f;
    __builtin_amdgcn_s_setprio(1);
#pragma unroll
    for (int qk = 0; qk < 2; ++qk)
#pragma unroll
      for (int kb = 0; kb < 2; ++kb)
#pragma unroll
        for (int ch = 0; ch < 4; ++ch)
          sac[qk][kb] = __builtin_amdgcn_mfma_f32_32x32x16_f16(ka[kb][ch], qf[qk][ch],
                                                               sac[qk][kb], 0, 0, 0);
    __builtin_amdgcn_s_setprio(0);

    f16x8 kn[2][4];
    if (i < 3) {
      const int tn = sp * 32 + (i + 1) * 8 + w;
#pragma unroll
      for (int kb = 0; kb < 2; ++kb)
#pragma unroll
        for (int ch = 0; ch < 4; ++ch)
          kn[kb][ch] = *(const f16x8*)(Kg + (size_t)(tn * 64 + kb * 32 + l31) * 64 + ch * 16 + h * 8);
    }

    // online softmax with defer-max
#pragma unroll
    for (int qk = 0; qk < 2; ++qk) {
      float mt = sac[qk][0][0];
#pragma unroll
      for (int kb = 0; kb < 2; ++kb)
#pragma unroll
        for (int r = 0; r < 16; ++r) mt = fmaxf(mt, sac[qk][kb][r]);
      mt = fmaxf(mt, __shfl_xor(mt, 32));
      if (__any(mt > mrun[qk] + RTHR)) {
        float nm   = fmaxf(mrun[qk], mt);
        float corr = exp2f(mrun[qk] - nm);
        lrun[qk] *= corr;
        mrun[qk] = nm;
#pragma unroll
        for (int db = 0; db < 2; ++db)
#pragma unroll
          for (int r = 0; r < 16; ++r) oacc[db][qk][r] *= corr;
      }
      float ts = 0.f;
#pragma unroll
      for (int kb = 0; kb < 2; ++kb)
#pragma unroll
        for (int r = 0; r < 16; ++r) {
          float pv = exp2f(sac[qk][kb][r] - mrun[qk]);
          sac[qk][kb][r] = pv;
          ts += pv;
        }
      ts += __shfl_xor(ts, 32);
      lrun[qk] += ts;
    }

    // P^T fragments in-register (cvt_pkrtz + xor-32 shuffle)
    f16x8 pf[2][4];
#pragma unroll
    for (int qk = 0; qk < 2; ++qk)
#pragma unroll
      for (int kb = 0; kb < 2; ++kb)
#pragma unroll
        for (int cp = 0; cp < 2; ++cp) {
          u32 lo0 = pkrtz(sac[qk][kb][8 * cp + 0], sac[qk][kb][8 * cp + 1]);
          u32 lo1 = pkrtz(sac[qk][kb][8 * cp + 2], sac[qk][kb][8 * cp + 3]);
          u32 hi0 = pkrtz(sac[qk][kb][8 * cp + 4], sac[qk][kb][8 * cp + 5]);
          u32 hi1 = pkrtz(sac[qk][kb][8 * cp + 6], sac[qk][kb][8 * cp + 7]);
          u32 ol0 = (u32)__shfl_xor((int)lo0, 32);
          u32 ol1 = (u32)__shfl_xor((int)lo1, 32);
          u32 oh0 = (u32)__shfl_xor((int)hi0, 32);
          u32 oh1 = (u32)__shfl_xor((int)hi1, 32);
          u32x4 pw;
          pw[0] = h ? oh0 : lo0;
          pw[1] = h ? oh1 : lo1;
          pw[2] = h ? hi0 : ol0;
          pw[3] = h ? hi1 : ol1;
          pf[qk][kb * 2 + cp] = __builtin_bit_cast(f16x8, pw);
        }

    __builtin_amdgcn_s_setprio(1);
#pragma unroll
    for (int db = 0; db < 2; ++db)
#pragma unroll
      for (int qk = 0; qk < 2; ++qk)
#pragma unroll
        for (int ch = 0; ch < 4; ++ch)
          oacc[db][qk] = __builtin_amdgcn_mfma_f32_32x32x16_f16(vf[db][ch], pf[qk][ch],
                                                                oacc[db][qk], 0, 0, 0);
    __builtin_amdgcn_s_setprio(0);

    if (i < 3) {
#pragma unroll
      for (int kb = 0; kb < 2; ++kb)
#pragma unroll
        for (int ch = 0; ch < 4; ++ch) ka[kb][ch] = kn[kb][ch];
    }
  }

  // ---- in-block merge across 8 waves (unnormalized; block (m,l) to ws) ----
  if (h == 0) {
#pragma unroll
    for (int qk = 0; qk < 2; ++qk) {
      mls[w][qk * 32 + l31][0] = mrun[qk];
      mls[w][qk * 32 + l31][1] = lrun[qk];
    }
  }
  for (int idx = tid; idx < 64 * 68; idx += 512) ((float*)oaccs)[idx] = 0.f;
  __syncthreads();

  float* Mm = (float*)((char*)ws + ML_B);
  float* Ll = Mm + 2 * MTOT;
  float wgt[2];
#pragma unroll
  for (int qk = 0; qk < 2; ++qk) {
    float mg = -INFINITY;
#pragma unroll
    for (int ww = 0; ww < 8; ++ww) mg = fmaxf(mg, mls[ww][qk * 32 + l31][0]);
    float lg = 0.f;
#pragma unroll
    for (int ww = 0; ww < 8; ++ww)
      lg += mls[ww][qk * 32 + l31][1] * exp2f(mls[ww][qk * 32 + l31][0] - mg);
    wgt[qk] = exp2f(mrun[qk] - mg);
    if (w == 0 && h == 0) {
      int row = qt * 64 + qk * 32 + l31;
      Mm[(size_t)sp * MTOT + row] = mg;
      Ll[(size_t)sp * MTOT + row] = lg;
    }
  }
#pragma unroll
  for (int db = 0; db < 2; ++db)
#pragma unroll
    for (int qk = 0; qk < 2; ++qk)
#pragma unroll
      for (int r = 0; r < 16; ++r) {
        int d = db * 32 + (r & 3) + 8 * (r >> 2) + 4 * h;
        atomicAdd(&oaccs[qk * 32 + l31][d], oacc[db][qk][r] * wgt[qk]);
      }
  __syncthreads();

  float* part = (float*)((char*)ws + PART_B) + (size_t)sp * MTOT * 64;
  for (int idx = tid; idx < 64 * 16; idx += 512) {
    int q = idx >> 4, c = (idx & 15) * 4;
    f32x4 v = *(const f32x4*)&oaccs[q][c];
    *(f32x4*)(part + (size_t)(qt * 64 + q) * 64 + c) = v;
  }
}

// ---------------- merge the 2 kv-splits ----------------
__global__ __launch_bounds__(256) void merge_kernel(const u16* __restrict__ ws,
                                                    float* __restrict__ out) {
  int gid = blockIdx.x * 256 + threadIdx.x;  // 262144 threads
  int row = gid >> 4, c = (gid & 15) * 4;
  const float* Mm = (const float*)((const char*)ws + ML_B);
  const float* Ll = Mm + 2 * MTOT;
  float m0 = Mm[row], m1 = Mm[MTOT + row];
  float mg = fmaxf(m0, m1);
  float w0 = exp2f(m0 - mg), w1 = exp2f(m1 - mg);
  float inv = 1.f / (w0 * Ll[row] + w1 * Ll[MTOT + row]);
  const float* p0 = (const float*)((const char*)ws + PART_B);
  const float* p1 = p0 + (size_t)MTOT * 64;
  f32x4 a = *(const f32x4*)(p0 + (size_t)row * 64 + c);
  f32x4 b = *(const f32x4*)(p1 + (size_t)row * 64 + c);
  f32x4 r = (a * w0 + b * w1) * inv;
  *(f32x4*)(out + (size_t)row * 64 + c) = r;
}

extern "C" void kernel_launch(void* const* d_in, const int* in_sizes, int n_in,
                              void* d_out, int out_size, void* d_ws, size_t ws_size,
                              hipStream_t stream) {
  const float* x  = (const float*)d_in[0];
  const float* Wq = (const float*)d_in[1];
  const float* Wk = (const float*)d_in[2];
  const float* Wv = (const float*)d_in[3];
  u16* ws = (u16*)d_ws;
  (void)in_sizes; (void)n_in; (void)out_size; (void)ws_size;

  wconv_kernel<<<96, 256, 0, stream>>>(Wq, Wk, Wv, ws + (W16_B >> 1));
  proj_kernel<<<512, 256, 0, stream>>>(x, ws + (W16_B >> 1), ws);
  attn_kernel<<<dim3(256, 2), 512, 0, stream>>>(ws);
  merge_kernel<<<1024, 256, 0, stream>>>(ws, (float*)d_out);
}

// Round 6
// 131.125 us; speedup vs baseline: 3.3453x; 3.3453x over previous
//
#include <hip/hip_runtime.h>
#include <hip/hip_bf16.h>

#define SEQ 4096
#define MTOT 16384

typedef float f32x4  __attribute__((ext_vector_type(4)));
typedef float f32x16 __attribute__((ext_vector_type(16)));
typedef _Float16 f16;
typedef _Float16 f16x8 __attribute__((ext_vector_type(8)));
typedef unsigned int   u32;
typedef unsigned int   u32x4 __attribute__((ext_vector_type(4)));
typedef unsigned short u16;

// ws byte offsets
static constexpr size_t QS_B  = 0;          // fp16 Q (pre-scaled) [16384][64]        2MB
static constexpr size_t KS_B  = 2u << 20;   // fp16 K [16384][64]                     2MB
static constexpr size_t VT_B  = 4u << 20;   // fp16 V^T tiled [4][128tile][64d][32kv] 2MB
static constexpr size_t W16_B = 6u << 20;   // fp16 W [192][512] (Wq scaled)        192KB

__device__ __forceinline__ u16 h16(float v) { return __builtin_bit_cast(u16, (f16)v); }
__device__ __forceinline__ u32 pkrtz(float a, float b) {
  return __builtin_bit_cast(u32, __builtin_amdgcn_cvt_pkrtz(a, b));
}

// ---------------- W fp32 -> fp16 (Wq folded with 0.125*log2e) ----------------
__global__ __launch_bounds__(256) void wconv_kernel(const float* __restrict__ Wq,
                                                    const float* __restrict__ Wk,
                                                    const float* __restrict__ Wv,
                                                    u16* __restrict__ w16) {
  const float QSC = 0.18033688011112042f;  // 0.125 * log2(e)
  int e = (blockIdx.x * 256 + threadIdx.x) * 4;  // [0, 98304)
  int mat = e >> 15;
  const float* W = (mat == 0) ? Wq : (mat == 1 ? Wk : Wv);
  f32x4 v = *(const f32x4*)(W + (e & 32767));
  if (mat == 0) v *= QSC;
  __attribute__((aligned(8))) u16 b[4];
#pragma unroll
  for (int j = 0; j < 4; ++j) b[j] = h16(v[j]);
  *(uint2*)(w16 + e) = *(uint2*)b;
}

// ---------------- QKV projection: direct-from-global fragments ----------------
// 512 blocks x 256 thr (4 waves). Block: 32 x-rows. Wave (mg,ng): rows mg*16..+15,
// cols ng*96..+95. K=512 in 16 steps of 32.
__global__ __launch_bounds__(256, 4) void proj_kernel(const float* __restrict__ x,
                                                      const u16* __restrict__ w16,
                                                      u16* __restrict__ ws) {
  __shared__ float scr[32 * 193];

  const int tid  = threadIdx.x;
  const int blk  = blockIdx.x;
  const int lane = tid & 63;
  const int w    = tid >> 6;
  const int r16  = lane & 15;
  const int g    = lane >> 4;
  const int mg   = w & 1;
  const int ng   = w >> 1;
  const int m0   = blk * 32 + mg * 16;

  f32x4 acc[6];
#pragma unroll
  for (int s = 0; s < 6; ++s) acc[s] = (f32x4){0.f, 0.f, 0.f, 0.f};

#pragma unroll 2
  for (int step = 0; step < 16; ++step) {
    const int k0 = step * 32;
    const float* xp = x + (size_t)(m0 + r16) * 512 + k0 + g * 8;
    f32x4 xa = *(const f32x4*)xp;
    f32x4 xb = *(const f32x4*)(xp + 4);
    f16x8 a;
#pragma unroll
    for (int j = 0; j < 4; ++j) { a[j] = (f16)xa[j]; a[4 + j] = (f16)xb[j]; }
#pragma unroll
    for (int s = 0; s < 6; ++s) {
      f16x8 b = *(const f16x8*)(w16 + (size_t)(ng * 96 + s * 16 + r16) * 512 + k0 + g * 8);
      acc[s] = __builtin_amdgcn_mfma_f32_16x16x32_f16(a, b, acc[s], 0, 0, 0);
    }
  }

  // dump to LDS scratch: row_local = mg*16 + g*4 + rr, col = ng*96 + s*16 + r16
#pragma unroll
  for (int s = 0; s < 6; ++s)
#pragma unroll
    for (int rr = 0; rr < 4; ++rr)
      scr[(mg * 16 + g * 4 + rr) * 193 + ng * 96 + s * 16 + r16] = acc[s][rr];
  __syncthreads();

  u16* Qs = ws + (QS_B >> 1);
  u16* Ks = ws + (KS_B >> 1);
  u16* Vt = ws + (VT_B >> 1);
  // Q and K rows (fp16, row-major)
  {
    int row = tid >> 3, c0 = (tid & 7) * 8;
    __attribute__((aligned(16))) u16 bq[8], bk[8];
#pragma unroll
    for (int j = 0; j < 8; ++j) {
      bq[j] = h16(scr[row * 193 + c0 + j]);
      bk[j] = h16(scr[row * 193 + 64 + c0 + j]);
    }
    *(uint4*)(Qs + (size_t)(blk * 32 + row) * 64 + c0) = *(uint4*)bq;
    *(uint4*)(Ks + (size_t)(blk * 32 + row) * 64 + c0) = *(uint4*)bk;
  }
  // V^T, kv-tiled layout [bb][tile][d][kvl]; this block is exactly one 32-kv tile
  {
    int d = tid >> 2, sg = (tid & 3) * 8;
    int bb = blk >> 7, tile = blk & 127;
    __attribute__((aligned(16))) u16 bv[8];
#pragma unroll
    for (int j = 0; j < 8; ++j) bv[j] = h16(scr[(sg + j) * 193 + 128 + d]);
    *(uint4*)(Vt + (((size_t)(bb * 128 + tile)) * 64 + d) * 32 + sg) = *(uint4*)bv;
  }
}

// ---------------- flash attention: 256 blocks x 1024 thr (16 waves = 4/SIMD) ----------
// wave (qh, sl): q rows qt*64 + qh*32 + l31, kv slice sl*512..+511 (16 iters of 32).
// Lean registers (~96 VGPR + 32 AGPR): no spill at 4 waves/SIMD. In-LDS 16-wave merge.
__global__ __launch_bounds__(1024, 4) void attn_kernel(const u16* __restrict__ ws,
                                                       float* __restrict__ out) {
  __shared__ float oaccs[64][68];
  __shared__ float mls[16][32][2];
  __shared__ float lsum[64];

  const int tid  = threadIdx.x;
  const int w    = tid >> 6;
  const int lane = tid & 63;
  const int l31  = lane & 31;
  const int h    = lane >> 5;
  const int qh   = w & 1;
  const int sl   = w >> 1;
  const int b    = blockIdx.x;
  const int qt   = (b & 7) * 32 + (b >> 3);  // XCD-bijective swizzle: XCD x -> batch x/2
  const int bb   = qt >> 6;

  const u16* Qg = ws + (QS_B >> 1);
  const u16* Kg = ws + (KS_B >> 1) + (size_t)bb * SEQ * 64;
  const u16* Vg = ws + (VT_B >> 1) + (size_t)bb * 128 * 64 * 32;

  // Q fragments (B-operand): lane holds Q[qt*64 + qh*32 + l31][ch*16 + h*8 + j]
  f16x8 qf[4];
#pragma unroll
  for (int ch = 0; ch < 4; ++ch)
    qf[ch] = *(const f16x8*)(Qg + (size_t)(qt * 64 + qh * 32 + l31) * 64 + ch * 16 + h * 8);

  f32x16 oacc[2];  // O^T [dblk], 32 AGPRs
#pragma unroll
  for (int db = 0; db < 2; ++db)
#pragma unroll
    for (int r = 0; r < 16; ++r) oacc[db][r] = 0.f;
  float mrun = -INFINITY, lrun = 0.f;
  const float RTHR = 11.0f;  // defer-max (exp2 domain): P <= 2^11, fp16-safe

#pragma unroll 1
  for (int it = 0; it < 16; ++it) {
    const int kv0 = sl * 512 + it * 32;
    // K fragments (A-operand)
    f16x8 ka[4];
#pragma unroll
    for (int ch = 0; ch < 4; ++ch)
      ka[ch] = *(const f16x8*)(Kg + (size_t)(kv0 + l31) * 64 + ch * 16 + h * 8);
    // V^T fragments (issued early; consumed after softmax)
    const int tile = sl * 16 + it;
    f16x8 vf[2][2];
#pragma unroll
    for (int db = 0; db < 2; ++db)
#pragma unroll
      for (int c2 = 0; c2 < 2; ++c2)
        vf[db][c2] = *(const f16x8*)(Vg + (((size_t)tile * 64) + db * 32 + l31) * 32 +
                                     c2 * 16 + h * 8);

    // S^T = K * Q^T
    f32x16 sac;
#pragma unroll
    for (int r = 0; r < 16; ++r) sac[r] = 0.f;
    __builtin_amdgcn_s_setprio(1);
#pragma unroll
    for (int ch = 0; ch < 4; ++ch)
      sac = __builtin_amdgcn_mfma_f32_32x32x16_f16(ka[ch], qf[ch], sac, 0, 0, 0);
    __builtin_amdgcn_s_setprio(0);

    // online softmax with defer-max; lane owns q-row l31, 16 of 32 kv
    float mt = sac[0];
#pragma unroll
    for (int r = 1; r < 16; ++r) mt = fmaxf(mt, sac[r]);
    mt = fmaxf(mt, __shfl_xor(mt, 32));
    if (__any(mt > mrun + RTHR)) {
      float nm   = fmaxf(mrun, mt);
      float corr = exp2f(mrun - nm);
      lrun *= corr;
      mrun = nm;
#pragma unroll
      for (int db = 0; db < 2; ++db)
#pragma unroll
        for (int r = 0; r < 16; ++r) oacc[db][r] *= corr;
    }
    float ts = 0.f;
#pragma unroll
    for (int r = 0; r < 16; ++r) {
      float pv = exp2f(sac[r] - mrun);
      sac[r] = pv;
      ts += pv;
    }
    ts += __shfl_xor(ts, 32);
    lrun += ts;

    // P^T B-fragments in-register (cvt_pkrtz + xor-32 shuffle), layout HW-verified r4
    f16x8 pf[2];
#pragma unroll
    for (int cp = 0; cp < 2; ++cp) {
      u32 lo0 = pkrtz(sac[8 * cp + 0], sac[8 * cp + 1]);
      u32 lo1 = pkrtz(sac[8 * cp + 2], sac[8 * cp + 3]);
      u32 hi0 = pkrtz(sac[8 * cp + 4], sac[8 * cp + 5]);
      u32 hi1 = pkrtz(sac[8 * cp + 6], sac[8 * cp + 7]);
      u32 ol0 = (u32)__shfl_xor((int)lo0, 32);
      u32 ol1 = (u32)__shfl_xor((int)lo1, 32);
      u32 oh0 = (u32)__shfl_xor((int)hi0, 32);
      u32 oh1 = (u32)__shfl_xor((int)hi1, 32);
      u32x4 pw;
      pw[0] = h ? oh0 : lo0;
      pw[1] = h ? oh1 : lo1;
      pw[2] = h ? hi0 : ol0;
      pw[3] = h ? hi1 : ol1;
      pf[cp] = __builtin_bit_cast(f16x8, pw);
    }

    // O^T += V^T * P^T
    __builtin_amdgcn_s_setprio(1);
#pragma unroll
    for (int db = 0; db < 2; ++db)
#pragma unroll
      for (int c2 = 0; c2 < 2; ++c2)
        oacc[db] = __builtin_amdgcn_mfma_f32_32x32x16_f16(vf[db][c2], pf[c2], oacc[db], 0, 0, 0);
    __builtin_amdgcn_s_setprio(0);
  }

  // ---- in-LDS merge across 16 waves ----
  if (h == 0) {
    mls[w][l31][0] = mrun;
    mls[w][l31][1] = lrun;
  }
  for (int idx = tid; idx < 64 * 68; idx += 1024) ((float*)oaccs)[idx] = 0.f;
  __syncthreads();

  float mg = -INFINITY;
#pragma unroll
  for (int ww = 0; ww < 8; ++ww) mg = fmaxf(mg, mls[ww * 2 + qh][l31][0]);
  float lg = 0.f;
#pragma unroll
  for (int ww = 0; ww < 8; ++ww)
    lg += mls[ww * 2 + qh][l31][1] * exp2f(mls[ww * 2 + qh][l31][0] - mg);
  float wgt = exp2f(mrun - mg);
  if (w < 2 && h == 0) lsum[qh * 32 + l31] = lg;

#pragma unroll
  for (int db = 0; db < 2; ++db)
#pragma unroll
    for (int r = 0; r < 16; ++r) {
      int d = db * 32 + (r & 3) + 8 * (r >> 2) + 4 * h;
      atomicAdd(&oaccs[qh * 32 + l31][d], oacc[db][r] * wgt);
    }
  __syncthreads();

  for (int idx = tid; idx < 64 * 16; idx += 1024) {
    int q = idx >> 4, c = (idx & 15) * 4;
    float inv = 1.f / lsum[q];
    f32x4 v = *(const f32x4*)&oaccs[q][c];
    v *= inv;
    *(f32x4*)(out + (size_t)(qt * 64 + q) * 64 + c) = v;
  }
}

extern "C" void kernel_launch(void* const* d_in, const int* in_sizes, int n_in,
                              void* d_out, int out_size, void* d_ws, size_t ws_size,
                              hipStream_t stream) {
  const float* x  = (const float*)d_in[0];
  const float* Wq = (const float*)d_in[1];
  const float* Wk = (const float*)d_in[2];
  const float* Wv = (const float*)d_in[3];
  u16* ws = (u16*)d_ws;
  (void)in_sizes; (void)n_in; (void)out_size; (void)ws_size;

  wconv_kernel<<<96, 256, 0, stream>>>(Wq, Wk, Wv, ws + (W16_B >> 1));
  proj_kernel<<<512, 256, 0, stream>>>(x, ws + (W16_B >> 1), ws);
  attn_kernel<<<256, 1024, 0, stream>>>(ws, (float*)d_out);
}